// Round 2
// baseline (896.480 us; speedup 1.0000x reference)
//
#include <hip/hip_runtime.h>

// mLSTM block, bf16-MFMA implementation (m97-style GEMM structure).
// Tokens M = 8*2048 = 16384, D = 1024, P = 2048, H = 1024.
//
// Pipeline:
//   ln1:   x[M,1024] f32 -> xn bf16
//   convT: 9 weights f32 [K,N] -> bf16 [N,K] (transposed for gemm_bt)
//   gemm:  xup = xn @ Wup + bup            [M,2048] bf16
//          xadj = xup @ Wadj + badj        [M,1024] bf16
//          q,k(,/8),v,i,f,o  = xadj @ W* + b*   bf16 each
//   ew:    gate math + LN2 + *sigmoid(xadj) -> y bf16
//   gemm:  out = y @ Wdn + bdn + x         [M,1024] f32
//
// Workspace layout (MiB offsets), TOTAL 246 MiB (fits a 256 MiB budget —
// R0's layout put weights at 256..278 MiB and memory-faulted):
//   [0,32)    xn    -> qb (xn dead after up-GEMM) -> yb (same-thread r/w alias)
//   [32,96)   xup   -> kb@[32,64), vb@[64,96) (xup dead after adj-GEMM)
//   [96,128)  xadj
//   [128,160) ib   [160,192) fb   [192,224) ob
//   [224,246) weights: WupT 4, WadjT 4, Wq/Wk/Wv/Wi/Wf/WoT 2 each, WdnT 2

typedef unsigned short u16;
typedef __attribute__((ext_vector_type(4))) unsigned short u16x4;
typedef __attribute__((ext_vector_type(8))) __bf16 bf16x8;
typedef __attribute__((ext_vector_type(4))) float f32x4;

__device__ __forceinline__ float bf2f(u16 u) {
    union { unsigned int i; float f; } c; c.i = ((unsigned int)u) << 16; return c.f;
}
__device__ __forceinline__ u16 f2bf(float f) {
    union { float f; unsigned int i; } c; c.f = f;
    unsigned int lsb = (c.i >> 16) & 1u;
    c.i += 0x7fffu + lsb;                 // round-to-nearest-even
    return (u16)(c.i >> 16);
}

// async global->LDS, 16B per lane; LDS dest = wave-uniform base + lane*16
#define GLDS16(gp, lp)                                                        \
    __builtin_amdgcn_global_load_lds(                                         \
        (__attribute__((address_space(1))) void*)(void*)(gp),                 \
        (__attribute__((address_space(3))) void*)(lp), 16, 0, 0)

#define BM 128
#define BN 128
#define BK 32

// C[M,N] = A[M,K] @ B[K,N] with Bt = B^T stored [N,K], all bf16, fp32 acc.
// MODE 0: out bf16 = (acc + bias[n]) * scale
// MODE 1: out f32  = (acc + bias[n]) * scale + resid[m*N+n]
template <int MODE>
__global__ __launch_bounds__(256) void gemm_bt(
    const u16* __restrict__ A, const u16* __restrict__ Bt,
    const float* __restrict__ bias, const float* __restrict__ resid,
    void* __restrict__ out, int M, int N, int K, float scale)
{
    __shared__ __align__(16) u16 As[BM * BK];
    __shared__ __align__(16) u16 Bs[BN * BK];

    const int tid  = threadIdx.x;
    const int lane = tid & 63;
    const int wave = tid >> 6;
    const int l15  = lane & 15;
    const int quad = lane >> 4;

    const long bm = (long)blockIdx.y * BM;
    const long bn = (long)blockIdx.x * BN;
    const int  wm = (wave >> 1) * 64;   // wave's 64x64 quadrant
    const int  wn = (wave & 1) * 64;

    f32x4 acc[4][4] = {};

    // staging: chunk c = i*256 + tid covers row c>>2, k-cols (c&3)*8..+7
    const int  r0 = tid >> 2;
    const int  ck = (tid & 3) * 8;
    const u16* ga0 = A  + (bm + r0) * (long)K + ck;
    const u16* gb0 = Bt + (bn + r0) * (long)K + ck;
    u16* lA = &As[(wave * 64) * 8];
    u16* lB = &Bs[(wave * 64) * 8];

    for (int k0 = 0; k0 < K; k0 += BK) {
        GLDS16(ga0 + k0, lA);
        GLDS16(ga0 + k0 + 64 * (long)K, lA + 256 * 8);
        GLDS16(gb0 + k0, lB);
        GLDS16(gb0 + k0 + 64 * (long)K, lB + 256 * 8);
        __syncthreads();

        bf16x8 af[4], bfr[4];
#pragma unroll
        for (int t = 0; t < 4; ++t) {
            af[t]  = *(const bf16x8*)&As[(wm + t * 16 + l15) * BK + quad * 8];
            bfr[t] = *(const bf16x8*)&Bs[(wn + t * 16 + l15) * BK + quad * 8];
        }
#pragma unroll
        for (int mt = 0; mt < 4; ++mt)
#pragma unroll
            for (int nt = 0; nt < 4; ++nt)
                acc[mt][nt] = __builtin_amdgcn_mfma_f32_16x16x32_bf16(
                    af[mt], bfr[nt], acc[mt][nt], 0, 0, 0);
        __syncthreads();
    }

    // C/D layout: col = lane&15, row = quad*4 + reg
#pragma unroll
    for (int nt = 0; nt < 4; ++nt) {
        const long n  = bn + wn + nt * 16 + l15;
        const float bv = bias[n];
#pragma unroll
        for (int mt = 0; mt < 4; ++mt) {
            const long m0 = bm + wm + mt * 16 + quad * 4;
#pragma unroll
            for (int r = 0; r < 4; ++r) {
                const long idx = (m0 + r) * N + n;
                const float val = (acc[mt][nt][r] + bv) * scale;
                if (MODE == 0) ((u16*)out)[idx] = f2bf(val);
                else           ((float*)out)[idx] = val + resid[idx];
            }
        }
    }
}

// LayerNorm over 1024 cols, fp32 in -> bf16 out. One 256-thread block per row.
__global__ __launch_bounds__(256) void ln_in_kernel(
    const float* __restrict__ x, const float* __restrict__ g,
    const float* __restrict__ b, u16* __restrict__ xn)
{
    const long row = blockIdx.x;
    const int  tid = threadIdx.x;
    const float4 v = ((const float4*)(x + row * 1024))[tid];
    float s  = v.x + v.y + v.z + v.w;
    float s2 = v.x * v.x + v.y * v.y + v.z * v.z + v.w * v.w;
#pragma unroll
    for (int off = 32; off > 0; off >>= 1) {
        s  += __shfl_down(s, off);
        s2 += __shfl_down(s2, off);
    }
    __shared__ float red[8];
    const int wave = tid >> 6;
    if ((tid & 63) == 0) { red[wave] = s; red[4 + wave] = s2; }
    __syncthreads();
    if (tid == 0) {
        const float S  = red[0] + red[1] + red[2] + red[3];
        const float S2 = red[4] + red[5] + red[6] + red[7];
        const float mu = S * (1.0f / 1024.0f);
        const float var = S2 * (1.0f / 1024.0f) - mu * mu;
        red[0] = mu; red[1] = rsqrtf(var + 1e-3f);
    }
    __syncthreads();
    const float mu = red[0], rstd = red[1];
    const int c = tid * 4;
    u16x4 o;
    o.x = f2bf((v.x - mu) * rstd * g[c + 0] + b[c + 0]);
    o.y = f2bf((v.y - mu) * rstd * g[c + 1] + b[c + 1]);
    o.z = f2bf((v.z - mu) * rstd * g[c + 2] + b[c + 2]);
    o.w = f2bf((v.w - mu) * rstd * g[c + 3] + b[c + 3]);
    *(u16x4*)(xn + row * 1024 + c) = o;
}

// transpose + f32->bf16: W[K,N] -> Wt[N,K]
__global__ __launch_bounds__(256) void convT_kernel(
    const float* __restrict__ W, u16* __restrict__ Wt, int K, int N)
{
    __shared__ float t[32][33];
    const int tx = threadIdx.x & 31;
    const int ty = threadIdx.x >> 5;
    const long bn = (long)blockIdx.x * 32;
    const long bk = (long)blockIdx.y * 32;
#pragma unroll
    for (int j = 0; j < 4; ++j)
        t[ty + j * 8][tx] = W[(bk + ty + j * 8) * N + bn + tx];
    __syncthreads();
#pragma unroll
    for (int j = 0; j < 4; ++j)
        Wt[(bn + ty + j * 8) * K + bk + tx] = f2bf(t[tx][ty + j * 8]);
}

// gate math + LN2 + sigmoid(xadj) product. One block per row of 1024.
// NOTE: y may alias q — each thread reads its gate values before writing
// y at the same flat offset; no cross-thread aliasing exists.
__global__ __launch_bounds__(256) void lstm_ew_kernel(
    const u16* __restrict__ q, const u16* __restrict__ k, const u16* __restrict__ v,
    const u16* __restrict__ it, const u16* __restrict__ ft, const u16* __restrict__ ot,
    const u16* __restrict__ xadj, const float* __restrict__ g2,
    const float* __restrict__ b2, u16* __restrict__ y)
{
    const long base = (long)blockIdx.x * 1024;
    const int  tid = threadIdx.x;
    const int  c = tid * 4;
    const u16x4 qv = *(const u16x4*)&q[base + c];
    const u16x4 kv = *(const u16x4*)&k[base + c];
    const u16x4 vv = *(const u16x4*)&v[base + c];
    const u16x4 iv = *(const u16x4*)&it[base + c];
    const u16x4 fv = *(const u16x4*)&ft[base + c];
    const u16x4 ov = *(const u16x4*)&ot[base + c];
    const u16x4 xv = *(const u16x4*)&xadj[base + c];

    float ht[4], sx[4];
    float s = 0.0f, s2 = 0.0f;
#pragma unroll
    for (int j = 0; j < 4; ++j) {
        const float qf = bf2f(qv[j]);
        const float kf = bf2f(kv[j]);          // already scaled by 1/8 in GEMM
        const float vf = bf2f(vv[j]);
        const float fi = bf2f(iv[j]);
        const float ff = bf2f(fv[j]);
        const float osig = 1.0f / (1.0f + __expf(-bf2f(ov[j])));
        const float mt = fmaxf(ff, fi);
        const float fe = __expf(ff - mt);
        const float ct = fe * vf * kf;
        const float h = osig * (ct * qf) / fmaxf(fabsf(kf * qf), 1.0f);
        ht[j] = h; s += h; s2 += h * h;
        sx[j] = 1.0f / (1.0f + __expf(-bf2f(xv[j])));
    }
#pragma unroll
    for (int off = 32; off > 0; off >>= 1) {
        s  += __shfl_down(s, off);
        s2 += __shfl_down(s2, off);
    }
    __shared__ float red[8];
    const int wave = tid >> 6;
    if ((tid & 63) == 0) { red[wave] = s; red[4 + wave] = s2; }
    __syncthreads();
    if (tid == 0) {
        const float S  = red[0] + red[1] + red[2] + red[3];
        const float S2 = red[4] + red[5] + red[6] + red[7];
        const float mu = S * (1.0f / 1024.0f);
        const float var = S2 * (1.0f / 1024.0f) - mu * mu;
        red[0] = mu; red[1] = rsqrtf(var + 1e-3f);
    }
    __syncthreads();
    const float mu = red[0], rstd = red[1];
    u16x4 o;
#pragma unroll
    for (int j = 0; j < 4; ++j)
        o[j] = f2bf(((ht[j] - mu) * rstd * g2[c + j] + b2[c + j]) * sx[j]);
    *(u16x4*)&y[base + c] = o;
}

extern "C" void kernel_launch(void* const* d_in, const int* in_sizes, int n_in,
                              void* d_out, int out_size, void* d_ws, size_t ws_size,
                              hipStream_t stream)
{
    const float* x    = (const float*)d_in[0];
    const float* g1   = (const float*)d_in[1];
    const float* b1   = (const float*)d_in[2];
    const float* Wup  = (const float*)d_in[3];
    const float* bup  = (const float*)d_in[4];
    const float* Wadj = (const float*)d_in[5];
    const float* badj = (const float*)d_in[6];
    const float* Wq = (const float*)d_in[7];   const float* bq = (const float*)d_in[8];
    const float* Wk = (const float*)d_in[9];   const float* bk = (const float*)d_in[10];
    const float* Wv = (const float*)d_in[11];  const float* bv = (const float*)d_in[12];
    const float* Wi = (const float*)d_in[13];  const float* bi = (const float*)d_in[14];
    const float* Wf = (const float*)d_in[15];  const float* bf = (const float*)d_in[16];
    const float* Wo = (const float*)d_in[17];  const float* bo = (const float*)d_in[18];
    const float* g2 = (const float*)d_in[19];  const float* b2 = (const float*)d_in[20];
    const float* Wdn = (const float*)d_in[21]; const float* bdn = (const float*)d_in[22];

    const int M = 8 * 2048;     // 16384 tokens
    const int D = 1024, P = 2048, H = 1024;

    char* ws = (char*)d_ws;
    const size_t MB = 1024 * 1024;
    u16* xn    = (u16*)(ws + 0);
    u16* xup   = (u16*)(ws + 32 * MB);
    u16* xadj  = (u16*)(ws + 96 * MB);
    u16* qb    = (u16*)(ws + 0);          // reuse xn (dead after up-GEMM)
    u16* kb    = (u16*)(ws + 32 * MB);    // reuse xup (dead after adj-GEMM)
    u16* vb    = (u16*)(ws + 64 * MB);
    u16* ib    = (u16*)(ws + 128 * MB);
    u16* fb    = (u16*)(ws + 160 * MB);
    u16* ob    = (u16*)(ws + 192 * MB);
    u16* yb    = (u16*)(ws + 0);          // alias qb (same-thread read-then-write)
    u16* WupT  = (u16*)(ws + 224 * MB);   // [2048,1024] 4MB
    u16* WadjT = (u16*)(ws + 228 * MB);   // [1024,2048] 4MB
    u16* WqT   = (u16*)(ws + 232 * MB);
    u16* WkT   = (u16*)(ws + 234 * MB);
    u16* WvT   = (u16*)(ws + 236 * MB);
    u16* WiT   = (u16*)(ws + 238 * MB);
    u16* WfT   = (u16*)(ws + 240 * MB);
    u16* WoT   = (u16*)(ws + 242 * MB);
    u16* WdnT  = (u16*)(ws + 244 * MB);   // ends at 246 MiB

    // 1) LN1
    ln_in_kernel<<<M, 256, 0, stream>>>(x, g1, b1, xn);

    // 2) weight transpose+convert
    convT_kernel<<<dim3(P / 32, D / 32), 256, 0, stream>>>(Wup,  WupT,  D, P);
    convT_kernel<<<dim3(H / 32, P / 32), 256, 0, stream>>>(Wadj, WadjT, P, H);
    convT_kernel<<<dim3(H / 32, H / 32), 256, 0, stream>>>(Wq,  WqT,  H, H);
    convT_kernel<<<dim3(H / 32, H / 32), 256, 0, stream>>>(Wk,  WkT,  H, H);
    convT_kernel<<<dim3(H / 32, H / 32), 256, 0, stream>>>(Wv,  WvT,  H, H);
    convT_kernel<<<dim3(H / 32, H / 32), 256, 0, stream>>>(Wi,  WiT,  H, H);
    convT_kernel<<<dim3(H / 32, H / 32), 256, 0, stream>>>(Wf,  WfT,  H, H);
    convT_kernel<<<dim3(H / 32, H / 32), 256, 0, stream>>>(Wo,  WoT,  H, H);
    convT_kernel<<<dim3(D / 32, H / 32), 256, 0, stream>>>(Wdn, WdnT, H, D);

    // 3) GEMM chain
    gemm_bt<0><<<dim3(P / BN, M / BM), 256, 0, stream>>>(xn,  WupT,  bup,  nullptr, xup,  M, P, D, 1.0f);
    gemm_bt<0><<<dim3(H / BN, M / BM), 256, 0, stream>>>(xup, WadjT, badj, nullptr, xadj, M, H, P, 1.0f);
    gemm_bt<0><<<dim3(H / BN, M / BM), 256, 0, stream>>>(xadj, WqT, bq, nullptr, qb, M, H, H, 1.0f);
    gemm_bt<0><<<dim3(H / BN, M / BM), 256, 0, stream>>>(xadj, WkT, bk, nullptr, kb, M, H, H, 0.125f);
    gemm_bt<0><<<dim3(H / BN, M / BM), 256, 0, stream>>>(xadj, WvT, bv, nullptr, vb, M, H, H, 1.0f);
    gemm_bt<0><<<dim3(H / BN, M / BM), 256, 0, stream>>>(xadj, WiT, bi, nullptr, ib, M, H, H, 1.0f);
    gemm_bt<0><<<dim3(H / BN, M / BM), 256, 0, stream>>>(xadj, WfT, bf, nullptr, fb, M, H, H, 1.0f);
    gemm_bt<0><<<dim3(H / BN, M / BM), 256, 0, stream>>>(xadj, WoT, bo, nullptr, ob, M, H, H, 1.0f);

    // 4) gates + LN2 + sigmoid(xadj)
    lstm_ew_kernel<<<M, 256, 0, stream>>>(qb, kb, vb, ib, fb, ob, xadj, g2, b2, yb);

    // 5) down-proj + bias + residual, fp32 out
    gemm_bt<1><<<dim3(D / BN, M / BM), 256, 0, stream>>>(yb, WdnT, bdn, x, (float*)d_out, M, D, H, 1.0f);
}

// Round 3
// 824.960 us; speedup vs baseline: 1.0867x; 1.0867x over previous
//
#include <hip/hip_runtime.h>

// mLSTM block, bf16-MFMA, R3: six gate GEMMs + gate math fused into one
// kernel (gemm_gates). Tokens M = 16384, D = 1024, P = 2048, H = 1024.
//
// Pipeline:
//   ln1:        x[M,1024] f32 -> xn bf16
//   convT:      weights f32 [K,N] -> bf16 [N,K]; 6 gate weights concatenated
//               into Wcat[6*1024,1024]
//   gemm_bt:    xup  = xn  @ Wup  + bup    [M,2048] bf16
//               xadj = xup @ Wadj + badj   [M,1024] bf16
//   gemm_gates: q,k,v,i,f,o (f32 accs, in-register) -> gate math -> ht bf16
//   ln2:        y = LN(ht) * sigmoid(xadj)          [M,1024] bf16
//   gemm_bt:    out = y @ Wdn + bdn + x             [M,1024] f32
//
// Workspace (MiB offsets), total 150 MiB:
//   [0,32)    xn -> ht (xn dead after up-GEMM) -> y (same-thread r/w alias)
//   [32,96)   xup
//   [96,128)  xadj
//   [128,132) WupT  [132,136) WadjT  [136,148) Wcat  [148,150) WdnT

typedef unsigned short u16;
typedef __attribute__((ext_vector_type(4))) unsigned short u16x4;
typedef __attribute__((ext_vector_type(8))) __bf16 bf16x8;
typedef __attribute__((ext_vector_type(4))) float f32x4;

__device__ __forceinline__ float bf2f(u16 u) {
    union { unsigned int i; float f; } c; c.i = ((unsigned int)u) << 16; return c.f;
}
__device__ __forceinline__ u16 f2bf(float f) {
    union { float f; unsigned int i; } c; c.f = f;
    unsigned int lsb = (c.i >> 16) & 1u;
    c.i += 0x7fffu + lsb;                 // round-to-nearest-even
    return (u16)(c.i >> 16);
}
__device__ __forceinline__ float sigmoidf(float z) {
    return 1.0f / (1.0f + __expf(-z));
}

// async global->LDS, 16B per lane; LDS dest = wave-uniform base + lane*16
#define GLDS16(gp, lp)                                                        \
    __builtin_amdgcn_global_load_lds(                                         \
        (__attribute__((address_space(1))) void*)(void*)(gp),                 \
        (__attribute__((address_space(3))) void*)(lp), 16, 0, 0)

#define BM 128
#define BN 128
#define BK 32

// C[M,N] = A[M,K] @ B[K,N] with Bt = B^T stored [N,K], all bf16, fp32 acc.
// MODE 0: out bf16 = (acc + bias[n]) * scale
// MODE 1: out f32  = (acc + bias[n]) * scale + resid[m*N+n]
template <int MODE>
__global__ __launch_bounds__(256) void gemm_bt(
    const u16* __restrict__ A, const u16* __restrict__ Bt,
    const float* __restrict__ bias, const float* __restrict__ resid,
    void* __restrict__ out, int M, int N, int K, float scale)
{
    __shared__ __align__(16) u16 As[BM * BK];
    __shared__ __align__(16) u16 Bs[BN * BK];

    const int tid  = threadIdx.x;
    const int lane = tid & 63;
    const int wave = tid >> 6;
    const int l15  = lane & 15;
    const int quad = lane >> 4;

    const long bm = (long)blockIdx.y * BM;
    const long bn = (long)blockIdx.x * BN;
    const int  wm = (wave >> 1) * 64;   // wave's 64x64 quadrant
    const int  wn = (wave & 1) * 64;

    f32x4 acc[4][4] = {};

    const int  r0 = tid >> 2;
    const int  ck = (tid & 3) * 8;
    const u16* ga0 = A  + (bm + r0) * (long)K + ck;
    const u16* gb0 = Bt + (bn + r0) * (long)K + ck;
    u16* lA = &As[(wave * 64) * 8];
    u16* lB = &Bs[(wave * 64) * 8];

    for (int k0 = 0; k0 < K; k0 += BK) {
        GLDS16(ga0 + k0, lA);
        GLDS16(ga0 + k0 + 64 * (long)K, lA + 256 * 8);
        GLDS16(gb0 + k0, lB);
        GLDS16(gb0 + k0 + 64 * (long)K, lB + 256 * 8);
        __syncthreads();

        bf16x8 af[4], bfr[4];
#pragma unroll
        for (int t = 0; t < 4; ++t) {
            af[t]  = *(const bf16x8*)&As[(wm + t * 16 + l15) * BK + quad * 8];
            bfr[t] = *(const bf16x8*)&Bs[(wn + t * 16 + l15) * BK + quad * 8];
        }
#pragma unroll
        for (int mt = 0; mt < 4; ++mt)
#pragma unroll
            for (int nt = 0; nt < 4; ++nt)
                acc[mt][nt] = __builtin_amdgcn_mfma_f32_16x16x32_bf16(
                    af[mt], bfr[nt], acc[mt][nt], 0, 0, 0);
        __syncthreads();
    }

    // C/D layout: col = lane&15, row = quad*4 + reg
#pragma unroll
    for (int nt = 0; nt < 4; ++nt) {
        const long n  = bn + wn + nt * 16 + l15;
        const float bv = bias[n];
#pragma unroll
        for (int mt = 0; mt < 4; ++mt) {
            const long m0 = bm + wm + mt * 16 + quad * 4;
#pragma unroll
            for (int r = 0; r < 4; ++r) {
                const long idx = (m0 + r) * N + n;
                const float val = (acc[mt][nt][r] + bv) * scale;
                if (MODE == 0) ((u16*)out)[idx] = f2bf(val);
                else           ((float*)out)[idx] = val + resid[idx];
            }
        }
    }
}

// Fused 6-way gate GEMM + mLSTM gate math.
// A = xadj [M,K], Wcat = 6 gate weights transposed, [6*1024, K] (order
// q,k,v,i,f,o). Per block: 64 (M) x 64 (N) tile of ALL six projections,
// f32 accumulators, gate math in-register, writes ht bf16 [M,1024].
__global__ __launch_bounds__(256) void gemm_gates(
    const u16* __restrict__ A, const u16* __restrict__ Wcat,
    const float* __restrict__ bq_, const float* __restrict__ bk_,
    const float* __restrict__ bv_, const float* __restrict__ bi_,
    const float* __restrict__ bf_, const float* __restrict__ bo_,
    u16* __restrict__ ht, int M, int N, int K)
{
    __shared__ __align__(16) u16 As[64 * 32];        // 4 KB
    __shared__ __align__(16) u16 Bs[6 * 64 * 32];    // 24 KB

    const int tid  = threadIdx.x;
    const int lane = tid & 63;
    const int wave = tid >> 6;
    const int l15  = lane & 15;
    const int quad = lane >> 4;

    const long bm = (long)blockIdx.y * 64;
    const long bn = (long)blockIdx.x * 64;
    const int  wm = (wave >> 1) * 32;   // wave's 32x32 quadrant (per gate)
    const int  wn = (wave & 1) * 32;

    f32x4 acc[6][2][2] = {};

    // staging: thread tid covers row tid>>2, k-cols (tid&3)*8..+7
    const int  r0 = tid >> 2;
    const int  ck = (tid & 3) * 8;
    const u16* ga = A    + (bm + r0) * (long)K + ck;
    const u16* gb = Wcat + (bn + r0) * (long)K + ck;   // gate g at +g*1024*K
    u16* lA = &As[wave * 512];          // wave w: rows 16w..16w+15
    u16* lB = &Bs[wave * 512];

    for (int k0 = 0; k0 < K; k0 += 32) {
        GLDS16(ga + k0, lA);
#pragma unroll
        for (int g = 0; g < 6; ++g)
            GLDS16(gb + (long)g * 1024 * K + k0, lB + g * 2048);
        __syncthreads();

        const bf16x8 af0 = *(const bf16x8*)&As[(wm + l15) * 32 + quad * 8];
        const bf16x8 af1 = *(const bf16x8*)&As[(wm + 16 + l15) * 32 + quad * 8];
#pragma unroll
        for (int g = 0; g < 6; ++g) {
            const bf16x8 b0 = *(const bf16x8*)&Bs[g * 2048 + (wn + l15) * 32 + quad * 8];
            const bf16x8 b1 = *(const bf16x8*)&Bs[g * 2048 + (wn + 16 + l15) * 32 + quad * 8];
            acc[g][0][0] = __builtin_amdgcn_mfma_f32_16x16x32_bf16(af0, b0, acc[g][0][0], 0, 0, 0);
            acc[g][0][1] = __builtin_amdgcn_mfma_f32_16x16x32_bf16(af0, b1, acc[g][0][1], 0, 0, 0);
            acc[g][1][0] = __builtin_amdgcn_mfma_f32_16x16x32_bf16(af1, b0, acc[g][1][0], 0, 0, 0);
            acc[g][1][1] = __builtin_amdgcn_mfma_f32_16x16x32_bf16(af1, b1, acc[g][1][1], 0, 0, 0);
        }
        __syncthreads();
    }

    // C/D layout: col = lane&15, row = quad*4 + reg. Gate math in f32.
#pragma unroll
    for (int nt = 0; nt < 2; ++nt) {
        const long n = bn + wn + nt * 16 + l15;
        const float bqn = bq_[n], bkn = bk_[n], bvn = bv_[n];
        const float bin = bi_[n], bfn = bf_[n], bon = bo_[n];
#pragma unroll
        for (int mt = 0; mt < 2; ++mt) {
            const long m0 = bm + wm + mt * 16 + quad * 4;
#pragma unroll
            for (int r = 0; r < 4; ++r) {
                const float qf = acc[0][mt][nt][r] + bqn;
                const float kf = (acc[1][mt][nt][r] + bkn) * 0.125f;
                const float vf = acc[2][mt][nt][r] + bvn;
                const float fi = acc[3][mt][nt][r] + bin;
                const float ff = acc[4][mt][nt][r] + bfn;
                const float osig = sigmoidf(acc[5][mt][nt][r] + bon);
                const float mx = fmaxf(ff, fi);
                const float fe = __expf(ff - mx);
                const float ct = fe * vf * kf;
                const float h  = osig * (ct * qf) / fmaxf(fabsf(kf * qf), 1.0f);
                ht[(m0 + r) * N + n] = f2bf(h);
            }
        }
    }
}

// LayerNorm over 1024 cols, fp32 in -> bf16 out. One 256-thread block per row.
__global__ __launch_bounds__(256) void ln_in_kernel(
    const float* __restrict__ x, const float* __restrict__ g,
    const float* __restrict__ b, u16* __restrict__ xn)
{
    const long row = blockIdx.x;
    const int  tid = threadIdx.x;
    const float4 v = ((const float4*)(x + row * 1024))[tid];
    float s  = v.x + v.y + v.z + v.w;
    float s2 = v.x * v.x + v.y * v.y + v.z * v.z + v.w * v.w;
#pragma unroll
    for (int off = 32; off > 0; off >>= 1) {
        s  += __shfl_down(s, off);
        s2 += __shfl_down(s2, off);
    }
    __shared__ float red[8];
    const int wave = tid >> 6;
    if ((tid & 63) == 0) { red[wave] = s; red[4 + wave] = s2; }
    __syncthreads();
    if (tid == 0) {
        const float S  = red[0] + red[1] + red[2] + red[3];
        const float S2 = red[4] + red[5] + red[6] + red[7];
        const float mu = S * (1.0f / 1024.0f);
        const float var = S2 * (1.0f / 1024.0f) - mu * mu;
        red[0] = mu; red[1] = rsqrtf(var + 1e-3f);
    }
    __syncthreads();
    const float mu = red[0], rstd = red[1];
    const int c = tid * 4;
    u16x4 o;
    o.x = f2bf((v.x - mu) * rstd * g[c + 0] + b[c + 0]);
    o.y = f2bf((v.y - mu) * rstd * g[c + 1] + b[c + 1]);
    o.z = f2bf((v.z - mu) * rstd * g[c + 2] + b[c + 2]);
    o.w = f2bf((v.w - mu) * rstd * g[c + 3] + b[c + 3]);
    *(u16x4*)(xn + row * 1024 + c) = o;
}

// transpose + f32->bf16: W[K,N] -> Wt[N,K]
__global__ __launch_bounds__(256) void convT_kernel(
    const float* __restrict__ W, u16* __restrict__ Wt, int K, int N)
{
    __shared__ float t[32][33];
    const int tx = threadIdx.x & 31;
    const int ty = threadIdx.x >> 5;
    const long bn = (long)blockIdx.x * 32;
    const long bk = (long)blockIdx.y * 32;
#pragma unroll
    for (int j = 0; j < 4; ++j)
        t[ty + j * 8][tx] = W[(bk + ty + j * 8) * N + bn + tx];
    __syncthreads();
#pragma unroll
    for (int j = 0; j < 4; ++j)
        Wt[(bn + ty + j * 8) * K + bk + tx] = f2bf(t[tx][ty + j * 8]);
}

// LN2 over ht rows + sigmoid(xadj) product. y may alias ht (same-thread r/w).
__global__ __launch_bounds__(256) void ln2_kernel(
    const u16* __restrict__ ht, const u16* __restrict__ xadj,
    const float* __restrict__ g2, const float* __restrict__ b2,
    u16* __restrict__ y)
{
    const long base = (long)blockIdx.x * 1024;
    const int  tid = threadIdx.x;
    const int  c = tid * 4;
    const u16x4 hv = *(const u16x4*)&ht[base + c];
    const u16x4 xv = *(const u16x4*)&xadj[base + c];

    float h[4];
    float s = 0.0f, s2 = 0.0f;
#pragma unroll
    for (int j = 0; j < 4; ++j) {
        h[j] = bf2f(hv[j]);
        s += h[j]; s2 += h[j] * h[j];
    }
#pragma unroll
    for (int off = 32; off > 0; off >>= 1) {
        s  += __shfl_down(s, off);
        s2 += __shfl_down(s2, off);
    }
    __shared__ float red[8];
    const int wave = tid >> 6;
    if ((tid & 63) == 0) { red[wave] = s; red[4 + wave] = s2; }
    __syncthreads();
    if (tid == 0) {
        const float S  = red[0] + red[1] + red[2] + red[3];
        const float S2 = red[4] + red[5] + red[6] + red[7];
        const float mu = S * (1.0f / 1024.0f);
        const float var = S2 * (1.0f / 1024.0f) - mu * mu;
        red[0] = mu; red[1] = rsqrtf(var + 1e-3f);
    }
    __syncthreads();
    const float mu = red[0], rstd = red[1];
    u16x4 o;
#pragma unroll
    for (int j = 0; j < 4; ++j)
        o[j] = f2bf(((h[j] - mu) * rstd * g2[c + j] + b2[c + j]) * sigmoidf(bf2f(xv[j])));
    *(u16x4*)&y[base + c] = o;
}

extern "C" void kernel_launch(void* const* d_in, const int* in_sizes, int n_in,
                              void* d_out, int out_size, void* d_ws, size_t ws_size,
                              hipStream_t stream)
{
    const float* x    = (const float*)d_in[0];
    const float* g1   = (const float*)d_in[1];
    const float* b1   = (const float*)d_in[2];
    const float* Wup  = (const float*)d_in[3];
    const float* bup  = (const float*)d_in[4];
    const float* Wadj = (const float*)d_in[5];
    const float* badj = (const float*)d_in[6];
    const float* Wq = (const float*)d_in[7];   const float* bq = (const float*)d_in[8];
    const float* Wk = (const float*)d_in[9];   const float* bk = (const float*)d_in[10];
    const float* Wv = (const float*)d_in[11];  const float* bv = (const float*)d_in[12];
    const float* Wi = (const float*)d_in[13];  const float* bi = (const float*)d_in[14];
    const float* Wf = (const float*)d_in[15];  const float* bf = (const float*)d_in[16];
    const float* Wo = (const float*)d_in[17];  const float* bo = (const float*)d_in[18];
    const float* g2 = (const float*)d_in[19];  const float* b2 = (const float*)d_in[20];
    const float* Wdn = (const float*)d_in[21]; const float* bdn = (const float*)d_in[22];

    const int M = 8 * 2048;     // 16384 tokens
    const int D = 1024, P = 2048, H = 1024;

    char* ws = (char*)d_ws;
    const size_t MB = 1024 * 1024;
    u16* xn    = (u16*)(ws + 0);
    u16* xup   = (u16*)(ws + 32 * MB);
    u16* xadj  = (u16*)(ws + 96 * MB);
    u16* htb   = (u16*)(ws + 0);          // reuse xn (dead after up-GEMM)
    u16* yb    = (u16*)(ws + 0);          // alias ht (same-thread read-then-write)
    u16* WupT  = (u16*)(ws + 128 * MB);   // [2048,1024] 4MB
    u16* WadjT = (u16*)(ws + 132 * MB);   // [1024,2048] 4MB
    u16* Wcat  = (u16*)(ws + 136 * MB);   // [6*1024,1024] 12MB, order q,k,v,i,f,o
    u16* WdnT  = (u16*)(ws + 148 * MB);   // [1024,1024] 2MB -> ends at 150 MiB

    // 1) LN1
    ln_in_kernel<<<M, 256, 0, stream>>>(x, g1, b1, xn);

    // 2) weight transpose+convert (gates go into concatenated Wcat)
    convT_kernel<<<dim3(P / 32, D / 32), 256, 0, stream>>>(Wup,  WupT,  D, P);
    convT_kernel<<<dim3(H / 32, P / 32), 256, 0, stream>>>(Wadj, WadjT, P, H);
    convT_kernel<<<dim3(H / 32, H / 32), 256, 0, stream>>>(Wq, Wcat + 0 * H * H, H, H);
    convT_kernel<<<dim3(H / 32, H / 32), 256, 0, stream>>>(Wk, Wcat + 1 * H * H, H, H);
    convT_kernel<<<dim3(H / 32, H / 32), 256, 0, stream>>>(Wv, Wcat + 2 * H * H, H, H);
    convT_kernel<<<dim3(H / 32, H / 32), 256, 0, stream>>>(Wi, Wcat + 3 * H * H, H, H);
    convT_kernel<<<dim3(H / 32, H / 32), 256, 0, stream>>>(Wf, Wcat + 4 * H * H, H, H);
    convT_kernel<<<dim3(H / 32, H / 32), 256, 0, stream>>>(Wo, Wcat + 5 * H * H, H, H);
    convT_kernel<<<dim3(D / 32, H / 32), 256, 0, stream>>>(Wdn, WdnT, H, D);

    // 3) up- and adj-GEMMs
    gemm_bt<0><<<dim3(P / BN, M / BM), 256, 0, stream>>>(xn,  WupT,  bup,  nullptr, xup,  M, P, D, 1.0f);
    gemm_bt<0><<<dim3(H / BN, M / BM), 256, 0, stream>>>(xup, WadjT, badj, nullptr, xadj, M, H, P, 1.0f);

    // 4) fused six-gate GEMM + gate math -> ht
    gemm_gates<<<dim3(H / 64, M / 64), 256, 0, stream>>>(
        xadj, Wcat, bq, bk, bv, bi, bf, bo, htb, M, H, H);

    // 5) LN2 + sigmoid(xadj) -> y
    ln2_kernel<<<M, 256, 0, stream>>>(htb, xadj, g2, b2, yb);

    // 6) down-proj + bias + residual, fp32 out
    gemm_bt<1><<<dim3(D / BN, M / BM), 256, 0, stream>>>(yb, WdnT, bdn, x, (float*)d_out, M, D, H, 1.0f);
}

// Round 4
// 808.576 us; speedup vs baseline: 1.1087x; 1.0203x over previous
//
#include <hip/hip_runtime.h>

// mLSTM block, bf16-MFMA, R4: LDS XOR-swizzle (bank-conflict-free fragment
// reads) in both GEMM kernels + gemm_gates restructured to mt=4,nt=1.
// Tokens M = 16384, D = 1024, P = 2048, H = 1024.
//
// LDS swizzle: tiles are [rows][32 u16] = 64 B rows = 4 chunks of 16 B.
// Chunk c of row r is STORED at chunk slot c ^ ((r>>1)&3). global_load_lds
// forces dest = base + lane*16, so the swizzle is applied to the SOURCE
// address each lane fetches. Fragment readers (row = ...+l15, chunk = quad)
// use quad ^ ((l15>>1)&3); the row-dependent term of (r>>1)&3 vanishes for
// all wm/t/wave offsets (multiples of 16 rows / 8 after >>1). Under the
// 8-consecutive-lane LDS service model, lanes 0..7 then hit all 32 banks
// exactly once -> conflict-free (was 4..8-way at 64 B stride).
//
// Workspace (MiB offsets), total 150 MiB:
//   [0,32)    xn -> ht (xn dead after up-GEMM) -> y (same-thread r/w alias)
//   [32,96)   xup
//   [96,128)  xadj
//   [128,132) WupT  [132,136) WadjT  [136,148) Wcat  [148,150) WdnT

typedef unsigned short u16;
typedef __attribute__((ext_vector_type(4))) unsigned short u16x4;
typedef __attribute__((ext_vector_type(8))) __bf16 bf16x8;
typedef __attribute__((ext_vector_type(4))) float f32x4;

__device__ __forceinline__ float bf2f(u16 u) {
    union { unsigned int i; float f; } c; c.i = ((unsigned int)u) << 16; return c.f;
}
__device__ __forceinline__ u16 f2bf(float f) {
    union { float f; unsigned int i; } c; c.f = f;
    unsigned int lsb = (c.i >> 16) & 1u;
    c.i += 0x7fffu + lsb;                 // round-to-nearest-even
    return (u16)(c.i >> 16);
}
__device__ __forceinline__ float sigmoidf(float z) {
    return 1.0f / (1.0f + __expf(-z));
}

// async global->LDS, 16B per lane; LDS dest = wave-uniform base + lane*16
#define GLDS16(gp, lp)                                                        \
    __builtin_amdgcn_global_load_lds(                                         \
        (__attribute__((address_space(1))) void*)(void*)(gp),                 \
        (__attribute__((address_space(3))) void*)(lp), 16, 0, 0)

#define BM 128
#define BN 128
#define BK 32

// C[M,N] = A[M,K] @ B[K,N] with Bt = B^T stored [N,K], all bf16, fp32 acc.
// MODE 0: out bf16 = (acc + bias[n]) * scale
// MODE 1: out f32  = (acc + bias[n]) * scale + resid[m*N+n]
template <int MODE>
__global__ __launch_bounds__(256) void gemm_bt(
    const u16* __restrict__ A, const u16* __restrict__ Bt,
    const float* __restrict__ bias, const float* __restrict__ resid,
    void* __restrict__ out, int M, int N, int K, float scale)
{
    __shared__ __align__(16) u16 As[BM * BK];
    __shared__ __align__(16) u16 Bs[BN * BK];

    const int tid  = threadIdx.x;
    const int lane = tid & 63;
    const int wave = tid >> 6;
    const int l15  = lane & 15;
    const int quad = lane >> 4;

    const long bm = (long)blockIdx.y * BM;
    const long bn = (long)blockIdx.x * BN;
    const int  wm = (wave >> 1) * 64;   // wave's 64x64 quadrant
    const int  wn = (wave & 1) * 64;

    f32x4 acc[4][4] = {};

    // staging: thread tid covers row tid>>2; SOURCE chunk is swizzled so the
    // identity LDS placement (lane*16) realizes the XOR-swizzled layout.
    const int  r0 = tid >> 2;
    const int  ck = (((tid & 3) ^ ((tid >> 3) & 3)) * 8);
    const u16* ga0 = A  + (bm + r0) * (long)K + ck;
    const u16* gb0 = Bt + (bn + r0) * (long)K + ck;
    u16* lA = &As[(wave * 64) * 8];
    u16* lB = &Bs[(wave * 64) * 8];

    const int q8s = (quad ^ ((l15 >> 1) & 3)) * 8;   // swizzled chunk offset

    for (int k0 = 0; k0 < K; k0 += BK) {
        GLDS16(ga0 + k0, lA);
        GLDS16(ga0 + k0 + 64 * (long)K, lA + 256 * 8);
        GLDS16(gb0 + k0, lB);
        GLDS16(gb0 + k0 + 64 * (long)K, lB + 256 * 8);
        __syncthreads();

        bf16x8 af[4], bfr[4];
#pragma unroll
        for (int t = 0; t < 4; ++t) {
            af[t]  = *(const bf16x8*)&As[(wm + t * 16 + l15) * BK + q8s];
            bfr[t] = *(const bf16x8*)&Bs[(wn + t * 16 + l15) * BK + q8s];
        }
#pragma unroll
        for (int mt = 0; mt < 4; ++mt)
#pragma unroll
            for (int nt = 0; nt < 4; ++nt)
                acc[mt][nt] = __builtin_amdgcn_mfma_f32_16x16x32_bf16(
                    af[mt], bfr[nt], acc[mt][nt], 0, 0, 0);
        __syncthreads();
    }

    // C/D layout: col = lane&15, row = quad*4 + reg
#pragma unroll
    for (int nt = 0; nt < 4; ++nt) {
        const long n  = bn + wn + nt * 16 + l15;
        const float bv = bias[n];
#pragma unroll
        for (int mt = 0; mt < 4; ++mt) {
            const long m0 = bm + wm + mt * 16 + quad * 4;
#pragma unroll
            for (int r = 0; r < 4; ++r) {
                const long idx = (m0 + r) * N + n;
                const float val = (acc[mt][nt][r] + bv) * scale;
                if (MODE == 0) ((u16*)out)[idx] = f2bf(val);
                else           ((float*)out)[idx] = val + resid[idx];
            }
        }
    }
}

// Fused 6-way gate GEMM + mLSTM gate math.
// A = xadj [M,K], Wcat = 6 gate weights transposed, [6*1024, K] (order
// q,k,v,i,f,o). Block = 64(M) x 64(N) of ALL six projections; wave w owns
// N-cols [16w,16w+16) x 64 M-rows x 6 gates (mt=4, nt=1): per K-step
// 4 A-reads + 6 B-reads feed 24 MFMAs. f32 accs, gate math in-register,
// writes ht bf16 [M,1024].
__global__ __launch_bounds__(256) void gemm_gates(
    const u16* __restrict__ A, const u16* __restrict__ Wcat,
    const float* __restrict__ bq_, const float* __restrict__ bk_,
    const float* __restrict__ bv_, const float* __restrict__ bi_,
    const float* __restrict__ bf_, const float* __restrict__ bo_,
    u16* __restrict__ ht, int M, int N, int K)
{
    __shared__ __align__(16) u16 As[64 * 32];        // 4 KB
    __shared__ __align__(16) u16 Bs[6 * 64 * 32];    // 24 KB

    const int tid  = threadIdx.x;
    const int lane = tid & 63;
    const int wave = tid >> 6;
    const int l15  = lane & 15;
    const int quad = lane >> 4;

    const long bm = (long)blockIdx.y * 64;
    const long bn = (long)blockIdx.x * 64;

    f32x4 acc[6][4] = {};

    // staging: thread tid covers row tid>>2, source chunk swizzled
    const int  r0 = tid >> 2;
    const int  ck = (((tid & 3) ^ ((tid >> 3) & 3)) * 8);
    const u16* ga = A    + (bm + r0) * (long)K + ck;
    const u16* gb = Wcat + (bn + r0) * (long)K + ck;   // gate g at +g*1024*K
    u16* lA = &As[wave * 512];          // wave w stages rows 16w..16w+15
    u16* lB = &Bs[wave * 512];

    const int q8s = (quad ^ ((l15 >> 1) & 3)) * 8;   // swizzled chunk offset
    const int brow = (wave * 16 + l15) * 32 + q8s;   // wave's B-frag row addr

    for (int k0 = 0; k0 < K; k0 += 32) {
        GLDS16(ga + k0, lA);
#pragma unroll
        for (int g = 0; g < 6; ++g)
            GLDS16(gb + (long)g * 1024 * K + k0, lB + g * 2048);
        __syncthreads();

        bf16x8 af[4];
#pragma unroll
        for (int t = 0; t < 4; ++t)
            af[t] = *(const bf16x8*)&As[(t * 16 + l15) * 32 + q8s];
#pragma unroll
        for (int g = 0; g < 6; ++g) {
            const bf16x8 bfrag = *(const bf16x8*)&Bs[g * 2048 + brow];
#pragma unroll
            for (int t = 0; t < 4; ++t)
                acc[g][t] = __builtin_amdgcn_mfma_f32_16x16x32_bf16(
                    af[t], bfrag, acc[g][t], 0, 0, 0);
        }
        __syncthreads();
    }

    // C/D layout: col = lane&15, row = quad*4 + reg. One n per lane.
    const long n = bn + wave * 16 + l15;
    const float bqn = bq_[n], bkn = bk_[n], bvn = bv_[n];
    const float bin = bi_[n], bfn = bf_[n], bon = bo_[n];
#pragma unroll
    for (int t = 0; t < 4; ++t) {
        const long m0 = bm + t * 16 + quad * 4;
#pragma unroll
        for (int r = 0; r < 4; ++r) {
            const float qf = acc[0][t][r] + bqn;
            const float kf = (acc[1][t][r] + bkn) * 0.125f;
            const float vf = acc[2][t][r] + bvn;
            const float fi = acc[3][t][r] + bin;
            const float ff = acc[4][t][r] + bfn;
            const float osig = sigmoidf(acc[5][t][r] + bon);
            const float mx = fmaxf(ff, fi);
            const float fe = __expf(ff - mx);
            const float ct = fe * vf * kf;
            const float h  = osig * (ct * qf) / fmaxf(fabsf(kf * qf), 1.0f);
            ht[(m0 + r) * N + n] = f2bf(h);
        }
    }
}

// LayerNorm over 1024 cols, fp32 in -> bf16 out. One 256-thread block per row.
__global__ __launch_bounds__(256) void ln_in_kernel(
    const float* __restrict__ x, const float* __restrict__ g,
    const float* __restrict__ b, u16* __restrict__ xn)
{
    const long row = blockIdx.x;
    const int  tid = threadIdx.x;
    const float4 v = ((const float4*)(x + row * 1024))[tid];
    float s  = v.x + v.y + v.z + v.w;
    float s2 = v.x * v.x + v.y * v.y + v.z * v.z + v.w * v.w;
#pragma unroll
    for (int off = 32; off > 0; off >>= 1) {
        s  += __shfl_down(s, off);
        s2 += __shfl_down(s2, off);
    }
    __shared__ float red[8];
    const int wave = tid >> 6;
    if ((tid & 63) == 0) { red[wave] = s; red[4 + wave] = s2; }
    __syncthreads();
    if (tid == 0) {
        const float S  = red[0] + red[1] + red[2] + red[3];
        const float S2 = red[4] + red[5] + red[6] + red[7];
        const float mu = S * (1.0f / 1024.0f);
        const float var = S2 * (1.0f / 1024.0f) - mu * mu;
        red[0] = mu; red[1] = rsqrtf(var + 1e-3f);
    }
    __syncthreads();
    const float mu = red[0], rstd = red[1];
    const int c = tid * 4;
    u16x4 o;
    o.x = f2bf((v.x - mu) * rstd * g[c + 0] + b[c + 0]);
    o.y = f2bf((v.y - mu) * rstd * g[c + 1] + b[c + 1]);
    o.z = f2bf((v.z - mu) * rstd * g[c + 2] + b[c + 2]);
    o.w = f2bf((v.w - mu) * rstd * g[c + 3] + b[c + 3]);
    *(u16x4*)(xn + row * 1024 + c) = o;
}

// transpose + f32->bf16: W[K,N] -> Wt[N,K]
__global__ __launch_bounds__(256) void convT_kernel(
    const float* __restrict__ W, u16* __restrict__ Wt, int K, int N)
{
    __shared__ float t[32][33];
    const int tx = threadIdx.x & 31;
    const int ty = threadIdx.x >> 5;
    const long bn = (long)blockIdx.x * 32;
    const long bk = (long)blockIdx.y * 32;
#pragma unroll
    for (int j = 0; j < 4; ++j)
        t[ty + j * 8][tx] = W[(bk + ty + j * 8) * N + bn + tx];
    __syncthreads();
#pragma unroll
    for (int j = 0; j < 4; ++j)
        Wt[(bn + ty + j * 8) * K + bk + tx] = f2bf(t[tx][ty + j * 8]);
}

// LN2 over ht rows + sigmoid(xadj) product. y may alias ht (same-thread r/w).
__global__ __launch_bounds__(256) void ln2_kernel(
    const u16* __restrict__ ht, const u16* __restrict__ xadj,
    const float* __restrict__ g2, const float* __restrict__ b2,
    u16* __restrict__ y)
{
    const long base = (long)blockIdx.x * 1024;
    const int  tid = threadIdx.x;
    const int  c = tid * 4;
    const u16x4 hv = *(const u16x4*)&ht[base + c];
    const u16x4 xv = *(const u16x4*)&xadj[base + c];

    float h[4];
    float s = 0.0f, s2 = 0.0f;
#pragma unroll
    for (int j = 0; j < 4; ++j) {
        h[j] = bf2f(hv[j]);
        s += h[j]; s2 += h[j] * h[j];
    }
#pragma unroll
    for (int off = 32; off > 0; off >>= 1) {
        s  += __shfl_down(s, off);
        s2 += __shfl_down(s2, off);
    }
    __shared__ float red[8];
    const int wave = tid >> 6;
    if ((tid & 63) == 0) { red[wave] = s; red[4 + wave] = s2; }
    __syncthreads();
    if (tid == 0) {
        const float S  = red[0] + red[1] + red[2] + red[3];
        const float S2 = red[4] + red[5] + red[6] + red[7];
        const float mu = S * (1.0f / 1024.0f);
        const float var = S2 * (1.0f / 1024.0f) - mu * mu;
        red[0] = mu; red[1] = rsqrtf(var + 1e-3f);
    }
    __syncthreads();
    const float mu = red[0], rstd = red[1];
    u16x4 o;
#pragma unroll
    for (int j = 0; j < 4; ++j)
        o[j] = f2bf(((h[j] - mu) * rstd * g2[c + j] + b2[c + j]) * sigmoidf(bf2f(xv[j])));
    *(u16x4*)&y[base + c] = o;
}

extern "C" void kernel_launch(void* const* d_in, const int* in_sizes, int n_in,
                              void* d_out, int out_size, void* d_ws, size_t ws_size,
                              hipStream_t stream)
{
    const float* x    = (const float*)d_in[0];
    const float* g1   = (const float*)d_in[1];
    const float* b1   = (const float*)d_in[2];
    const float* Wup  = (const float*)d_in[3];
    const float* bup  = (const float*)d_in[4];
    const float* Wadj = (const float*)d_in[5];
    const float* badj = (const float*)d_in[6];
    const float* Wq = (const float*)d_in[7];   const float* bq = (const float*)d_in[8];
    const float* Wk = (const float*)d_in[9];   const float* bk = (const float*)d_in[10];
    const float* Wv = (const float*)d_in[11];  const float* bv = (const float*)d_in[12];
    const float* Wi = (const float*)d_in[13];  const float* bi = (const float*)d_in[14];
    const float* Wf = (const float*)d_in[15];  const float* bf = (const float*)d_in[16];
    const float* Wo = (const float*)d_in[17];  const float* bo = (const float*)d_in[18];
    const float* g2 = (const float*)d_in[19];  const float* b2 = (const float*)d_in[20];
    const float* Wdn = (const float*)d_in[21]; const float* bdn = (const float*)d_in[22];

    const int M = 8 * 2048;     // 16384 tokens
    const int D = 1024, P = 2048, H = 1024;

    char* ws = (char*)d_ws;
    const size_t MB = 1024 * 1024;
    u16* xn    = (u16*)(ws + 0);
    u16* xup   = (u16*)(ws + 32 * MB);
    u16* xadj  = (u16*)(ws + 96 * MB);
    u16* htb   = (u16*)(ws + 0);          // reuse xn (dead after up-GEMM)
    u16* yb    = (u16*)(ws + 0);          // alias ht (same-thread read-then-write)
    u16* WupT  = (u16*)(ws + 128 * MB);   // [2048,1024] 4MB
    u16* WadjT = (u16*)(ws + 132 * MB);   // [1024,2048] 4MB
    u16* Wcat  = (u16*)(ws + 136 * MB);   // [6*1024,1024] 12MB, order q,k,v,i,f,o
    u16* WdnT  = (u16*)(ws + 148 * MB);   // [1024,1024] 2MB -> ends at 150 MiB

    // 1) LN1
    ln_in_kernel<<<M, 256, 0, stream>>>(x, g1, b1, xn);

    // 2) weight transpose+convert (gates go into concatenated Wcat)
    convT_kernel<<<dim3(P / 32, D / 32), 256, 0, stream>>>(Wup,  WupT,  D, P);
    convT_kernel<<<dim3(H / 32, P / 32), 256, 0, stream>>>(Wadj, WadjT, P, H);
    convT_kernel<<<dim3(H / 32, H / 32), 256, 0, stream>>>(Wq, Wcat + 0 * H * H, H, H);
    convT_kernel<<<dim3(H / 32, H / 32), 256, 0, stream>>>(Wk, Wcat + 1 * H * H, H, H);
    convT_kernel<<<dim3(H / 32, H / 32), 256, 0, stream>>>(Wv, Wcat + 2 * H * H, H, H);
    convT_kernel<<<dim3(H / 32, H / 32), 256, 0, stream>>>(Wi, Wcat + 3 * H * H, H, H);
    convT_kernel<<<dim3(H / 32, H / 32), 256, 0, stream>>>(Wf, Wcat + 4 * H * H, H, H);
    convT_kernel<<<dim3(H / 32, H / 32), 256, 0, stream>>>(Wo, Wcat + 5 * H * H, H, H);
    convT_kernel<<<dim3(D / 32, H / 32), 256, 0, stream>>>(Wdn, WdnT, H, D);

    // 3) up- and adj-GEMMs
    gemm_bt<0><<<dim3(P / BN, M / BM), 256, 0, stream>>>(xn,  WupT,  bup,  nullptr, xup,  M, P, D, 1.0f);
    gemm_bt<0><<<dim3(H / BN, M / BM), 256, 0, stream>>>(xup, WadjT, badj, nullptr, xadj, M, H, P, 1.0f);

    // 4) fused six-gate GEMM + gate math -> ht
    gemm_gates<<<dim3(H / 64, M / 64), 256, 0, stream>>>(
        xadj, Wcat, bq, bk, bv, bi, bf, bo, htb, M, H, H);

    // 5) LN2 + sigmoid(xadj) -> y
    ln2_kernel<<<M, 256, 0, stream>>>(htb, xadj, g2, b2, yb);

    // 6) down-proj + bias + residual, fp32 out
    gemm_bt<1><<<dim3(D / BN, M / BM), 256, 0, stream>>>(yb, WdnT, bdn, x, (float*)d_out, M, D, H, 1.0f);
}